// Round 6
// baseline (467.326 us; speedup 1.0000x reference)
//
#include <hip/hip_runtime.h>
#include <math.h>
#include <stdint.h>

#define HID 128
#define NBUCK_MAX 512     // node buckets of 256 nodes each (nN<=131072)
#define EDGE_TILE 8192    // edges per block in bucket passes
#define GEMM_ROWS 128     // M-tile per block (layer-0 gemm)
#define XS_STRIDE 136     // bf16 elems per LDS row (128 + 8 pad)

typedef short bf16x8 __attribute__((ext_vector_type(8)));
typedef float f32x4 __attribute__((ext_vector_type(4)));

// ---------------------------------------------------------------------------
// round-to-nearest-even fp32 -> bf16 bits
__device__ __forceinline__ unsigned int f2bf(float f) {
    union { float f; uint32_t i; } u; u.f = f;
    uint32_t r = u.i + 0x7fffu + ((u.i >> 16) & 1u);
    return r >> 16;
}
__device__ __forceinline__ float bf2f_lo(uint32_t x) {
    union { uint32_t i; float f; } t; t.i = x << 16; return t.f;
}
__device__ __forceinline__ float bf2f_hi(uint32_t x) {
    union { uint32_t i; float f; } t; t.i = x & 0xffff0000u; return t.f;
}

// ---------------------------------------------------------------------------
// Multisplit pass 1: per-bucket counts (bucket = dst >> 8) + fused weight
// transpose/convert: Wt[n][k] = bf16(W[k][n]), 3 x 128 x 128.
__global__ __launch_bounds__(256) void bucket_count_wt(const int* __restrict__ dst,
                                                       int* __restrict__ bcnt,
                                                       const float* __restrict__ W0,
                                                       const float* __restrict__ W1,
                                                       const float* __restrict__ W2,
                                                       unsigned short* __restrict__ Wtb,
                                                       int nE, int nB) {
    __shared__ int h[NBUCK_MAX];
    const int gid = blockIdx.x * 256 + threadIdx.x;
    if (gid < 3 * HID * HID) {          // fused weight transpose (49152 elems)
        int w = gid >> 14, r = gid & 16383;
        int n = r >> 7, k = r & 127;
        const float* W = (w == 0) ? W0 : (w == 1) ? W1 : W2;
        Wtb[gid] = (unsigned short)f2bf(W[k * HID + n]);
    }
    for (int i = threadIdx.x; i < nB; i += 256) h[i] = 0;
    __syncthreads();
    const int base = blockIdx.x * EDGE_TILE;
    const int end = min(base + EDGE_TILE, nE);
    for (int e = base + threadIdx.x; e < end; e += 256)
        atomicAdd(&h[dst[e] >> 8], 1);
    __syncthreads();
    for (int i = threadIdx.x; i < nB; i += 256)
        if (h[i]) atomicAdd(&bcnt[i], h[i]);
}

__global__ __launch_bounds__(512) void bucket_scan(const int* __restrict__ bcnt,
                                                   int* __restrict__ boff,
                                                   int* __restrict__ bcur, int nB) {
    __shared__ int sd[512];
    const int t = threadIdx.x;
    sd[t] = (t < nB) ? bcnt[t] : 0;
    __syncthreads();
#pragma unroll
    for (int off = 1; off < 512; off <<= 1) {
        int v = sd[t];
        int add = (t >= off) ? sd[t - off] : 0;
        __syncthreads();
        sd[t] = v + add;
        __syncthreads();
    }
    if (t < nB) {
        int ex = (t > 0) ? sd[t - 1] : 0;
        boff[t] = ex;
        bcur[t] = ex;
    }
}

__global__ __launch_bounds__(256) void bucket_scatter(const int* __restrict__ src,
                                                      const int* __restrict__ dst,
                                                      int* __restrict__ bcur,
                                                      unsigned int* __restrict__ ebuf,
                                                      int nE, int nB) {
    __shared__ int h[NBUCK_MAX];
    __shared__ int basearr[NBUCK_MAX];
    const int base = blockIdx.x * EDGE_TILE;
    const int end = min(base + EDGE_TILE, nE);
    for (int i = threadIdx.x; i < nB; i += 256) h[i] = 0;
    __syncthreads();
    for (int e = base + threadIdx.x; e < end; e += 256)
        atomicAdd(&h[dst[e] >> 8], 1);
    __syncthreads();
    for (int i = threadIdx.x; i < nB; i += 256) {
        int c = h[i];
        basearr[i] = c ? atomicAdd(&bcur[i], c) : 0;
        h[i] = 0;   // reuse as local cursor
    }
    __syncthreads();
    for (int e = base + threadIdx.x; e < end; e += 256) {
        int d = dst[e];
        int b = d >> 8;
        int pos = basearr[b] + atomicAdd(&h[b], 1);
        ebuf[pos] = ((unsigned)src[e] << 8) | ((unsigned)d & 255u);
    }
}

// ---------------------------------------------------------------------------
// Merged CSR build: one block per 256-node bucket. boff[b] (bucket-boundary
// edge prefix) IS the global CSR prefix, so no inter-block scan is needed.
// histogram -> local exclusive scan (+boff[b]) -> rowptr/dinv -> in-LDS scatter.
// The bucket's ebuf segment (~16KB) stays L1-hot for the second read.
__global__ __launch_bounds__(256) void csr_build(const unsigned int* __restrict__ ebuf,
                                                 const int* __restrict__ boff,
                                                 float* __restrict__ dinv,
                                                 int* __restrict__ rowptr,
                                                 int* __restrict__ ssrc,
                                                 int nE, int nB, int nN) {
    __shared__ int h[256];
    __shared__ int rp[256];
    const int b = blockIdx.x, t = threadIdx.x;
    const int e0 = boff[b];
    const int e1 = (b + 1 < nB) ? boff[b + 1] : nE;
    h[t] = 0;
    __syncthreads();
    for (int e = e0 + t; e < e1; e += 256)
        atomicAdd(&h[ebuf[e] & 255u], 1);
    __syncthreads();
    const int c = h[t];
    rp[t] = c;
    __syncthreads();
#pragma unroll
    for (int off = 1; off < 256; off <<= 1) {
        int v = rp[t];
        int add = (t >= off) ? rp[t - off] : 0;
        __syncthreads();
        rp[t] = v + add;
        __syncthreads();
    }
    const int pre = e0 + rp[t] - c;     // exclusive global prefix for node
    const int v = b * 256 + t;
    if (v < nN) {
        rowptr[v] = pre;
        dinv[v] = rsqrtf((float)c + 1.0f);
    }
    if (b == 0 && t == 0) rowptr[nN] = nE;
    __syncthreads();
    rp[t] = pre;                        // scatter base
    h[t] = 0;                           // cursor
    __syncthreads();
    for (int e = e0 + t; e < e1; e += 256) {
        unsigned int ed = ebuf[e];
        int li = (int)(ed & 255u);
        int pos = rp[li] + atomicAdd(&h[li], 1);
        ssrc[pos] = (int)(ed >> 8);
    }
}

// ---------------------------------------------------------------------------
// Layer-0 MFMA GEMM with fused fp32->bf16 input conversion.
// Pb = bf16(dinv ⊙ (bf16(X) @ W)), fp32 accumulate. X loads non-temporal
// (51 MB read-once stream; don't pollute L2).
__global__ __launch_bounds__(256) void gemm_mfma_f32in(const float* __restrict__ X,
                                                       const uint4* __restrict__ Wtb,
                                                       const float* __restrict__ dinv,
                                                       unsigned int* __restrict__ Pb32,
                                                       int nN) {
    __shared__ short Xs[GEMM_ROWS * XS_STRIDE];
    __shared__ short Ws[HID * XS_STRIDE];
    const int tid = threadIdx.x;
    const int rowBase = blockIdx.x * GEMM_ROWS;
#pragma unroll
    for (int it = 0; it < 16; ++it) {  // 4096 float4 X-tile, convert to bf16
        int f = it * 256 + tid;
        int row = f >> 5, c = f & 31;
        int grow = rowBase + row;
        f32x4 v = {0.f, 0.f, 0.f, 0.f};
        if (grow < nN)
            v = __builtin_nontemporal_load((const f32x4*)(X + (size_t)grow * HID + c * 4));
        uint2 o;
        o.x = f2bf(v[0]) | (f2bf(v[1]) << 16);
        o.y = f2bf(v[2]) | (f2bf(v[3]) << 16);
        *(uint2*)(&Xs[row * XS_STRIDE + c * 4]) = o;
    }
#pragma unroll
    for (int it = 0; it < 8; ++it) {   // 2048 uint4 W-tile
        int f = it * 256 + tid;
        int n = f >> 4, c = f & 15;
        *(uint4*)(&Ws[n * XS_STRIDE + c * 8]) = Wtb[f];
    }
    __syncthreads();
    const int wave = tid >> 6, lane = tid & 63;
    const int quad = lane >> 4, l16 = lane & 15;
    f32x4 acc[2][8] = {};
    const int kq = quad * 8;
#pragma unroll
    for (int ks = 0; ks < 4; ++ks) {
        const int k0 = ks * 32 + kq;
        bf16x8 a0 = *(const bf16x8*)(&Xs[(wave * 32 + l16) * XS_STRIDE + k0]);
        bf16x8 a1 = *(const bf16x8*)(&Xs[(wave * 32 + 16 + l16) * XS_STRIDE + k0]);
#pragma unroll
        for (int nt = 0; nt < 8; ++nt) {
            bf16x8 b = *(const bf16x8*)(&Ws[(nt * 16 + l16) * XS_STRIDE + k0]);
            acc[0][nt] = __builtin_amdgcn_mfma_f32_16x16x32_bf16(a0, b, acc[0][nt], 0, 0, 0);
            acc[1][nt] = __builtin_amdgcn_mfma_f32_16x16x32_bf16(a1, b, acc[1][nt], 0, 0, 0);
        }
    }
#pragma unroll
    for (int mt = 0; mt < 2; ++mt) {
        const int gr0 = rowBase + wave * 32 + mt * 16 + quad * 4;
#pragma unroll
        for (int r = 0; r < 4; ++r) {
            const int gr = gr0 + r;
            const bool ok = gr < nN;
            const float d = ok ? dinv[gr] : 0.f;
#pragma unroll
            for (int nt = 0; nt < 8; ++nt) {
                float v = d * acc[mt][nt][r];
                float vo = __shfl_xor(v, 1, 64);
                if (ok && !(l16 & 1)) {
                    Pb32[(size_t)gr * 64 + nt * 8 + (l16 >> 1)] = f2bf(v) | (f2bf(vo) << 16);
                }
            }
        }
    }
}

// ---------------------------------------------------------------------------
// unpack 8 bf16 (uint4) and accumulate into 8 fp32
__device__ __forceinline__ void acc_bf8(const uint4 q, float* a) {
    union { uint32_t i; float f; } t;
    t.i = q.x << 16;          a[0] += t.f;
    t.i = q.x & 0xffff0000u;  a[1] += t.f;
    t.i = q.y << 16;          a[2] += t.f;
    t.i = q.y & 0xffff0000u;  a[3] += t.f;
    t.i = q.z << 16;          a[4] += t.f;
    t.i = q.z & 0xffff0000u;  a[5] += t.f;
    t.i = q.w << 16;          a[6] += t.f;
    t.i = q.w & 0xffff0000u;  a[7] += t.f;
}

// Fused agg + next-layer GEMM:
// h[v] = relu(dinv[v]*(P[v] + sum_in P[src]) + b)   (gather phase, registers)
// Pout[v] = bf16(dinv[v] * (h @ Wnext)[v])          (LDS h-tile + MFMA)
// ssrc loads + Pout stores are non-temporal: protect the L2-resident Pb rows
// (the 16x-reused gather payload) from our own streaming traffic.
__global__ __launch_bounds__(256) void fused_agg_gemm(const uint4* __restrict__ Pb,
                                                      const int* __restrict__ rowptr,
                                                      const int* __restrict__ ssrc,
                                                      const float* __restrict__ dinv,
                                                      const float* __restrict__ bias,
                                                      const uint4* __restrict__ Wtb,
                                                      unsigned int* __restrict__ Pout32,
                                                      int nN) {
    __shared__ short Ws[HID * XS_STRIDE];  // 34816 B
    __shared__ short Hs[16 * XS_STRIDE];   //  4352 B
    const int tid = threadIdx.x;
#pragma unroll
    for (int it = 0; it < 8; ++it) {       // stage W (2048 uint4)
        int f = it * 256 + tid;
        int n = f >> 4, c = f & 15;
        *(uint4*)(&Ws[n * XS_STRIDE + c * 8]) = Wtb[f];
    }
    const int lane16 = tid & 15;
    const int grp = tid >> 4;
    const int v = blockIdx.x * 16 + grp;
    const bool ok = v < nN;
    float a0[8], a1[8], a2[8], a3[8];
#pragma unroll
    for (int i = 0; i < 8; ++i) { a0[i] = 0.f; a1[i] = 0.f; a2[i] = 0.f; a3[i] = 0.f; }
    uint4 q = make_uint4(0u, 0u, 0u, 0u);
    if (ok) {
        acc_bf8(Pb[(size_t)v * 16 + lane16], a0);  // self loop
        int e = rowptr[v];
        const int e1 = rowptr[v + 1];
        for (; e + 4 <= e1; e += 4) {
            const int u0 = __builtin_nontemporal_load(ssrc + e + 0);
            const int u1 = __builtin_nontemporal_load(ssrc + e + 1);
            const int u2 = __builtin_nontemporal_load(ssrc + e + 2);
            const int u3 = __builtin_nontemporal_load(ssrc + e + 3);
            uint4 q0 = Pb[(size_t)u0 * 16 + lane16];
            uint4 q1 = Pb[(size_t)u1 * 16 + lane16];
            uint4 q2 = Pb[(size_t)u2 * 16 + lane16];
            uint4 q3 = Pb[(size_t)u3 * 16 + lane16];
            acc_bf8(q0, a0); acc_bf8(q1, a1); acc_bf8(q2, a2); acc_bf8(q3, a3);
        }
        for (; e < e1; ++e) {
            const int u = __builtin_nontemporal_load(ssrc + e);
            uint4 qe = Pb[(size_t)u * 16 + lane16];
            acc_bf8(qe, a1);
        }
        const float dv = dinv[v];
        const float4 bb0 = ((const float4*)bias)[lane16 * 2];
        const float4 bb1 = ((const float4*)bias)[lane16 * 2 + 1];
        float4 o0, o1;
        o0.x = fmaxf(fmaf(dv, (a0[0] + a1[0]) + (a2[0] + a3[0]), bb0.x), 0.f);
        o0.y = fmaxf(fmaf(dv, (a0[1] + a1[1]) + (a2[1] + a3[1]), bb0.y), 0.f);
        o0.z = fmaxf(fmaf(dv, (a0[2] + a1[2]) + (a2[2] + a3[2]), bb0.z), 0.f);
        o0.w = fmaxf(fmaf(dv, (a0[3] + a1[3]) + (a2[3] + a3[3]), bb0.w), 0.f);
        o1.x = fmaxf(fmaf(dv, (a0[4] + a1[4]) + (a2[4] + a3[4]), bb1.x), 0.f);
        o1.y = fmaxf(fmaf(dv, (a0[5] + a1[5]) + (a2[5] + a3[5]), bb1.y), 0.f);
        o1.z = fmaxf(fmaf(dv, (a0[6] + a1[6]) + (a2[6] + a3[6]), bb1.z), 0.f);
        o1.w = fmaxf(fmaf(dv, (a0[7] + a1[7]) + (a2[7] + a3[7]), bb1.w), 0.f);
        q.x = f2bf(o0.x) | (f2bf(o0.y) << 16);
        q.y = f2bf(o0.z) | (f2bf(o0.w) << 16);
        q.z = f2bf(o1.x) | (f2bf(o1.y) << 16);
        q.w = f2bf(o1.z) | (f2bf(o1.w) << 16);
    }
    *(uint4*)(&Hs[grp * XS_STRIDE + lane16 * 8]) = q;  // bf16 h row tile
    __syncthreads();
    // MFMA: each wave computes the 16-row tile x its 32 cols
    const int wave = tid >> 6, lane = tid & 63;
    const int quad = lane >> 4, l16 = lane & 15;
    f32x4 acc[2] = {};
#pragma unroll
    for (int ks = 0; ks < 4; ++ks) {
        const int k0 = ks * 32 + quad * 8;
        bf16x8 a = *(const bf16x8*)(&Hs[l16 * XS_STRIDE + k0]);
#pragma unroll
        for (int nt = 0; nt < 2; ++nt) {
            bf16x8 b = *(const bf16x8*)(&Ws[((wave * 2 + nt) * 16 + l16) * XS_STRIDE + k0]);
            acc[nt] = __builtin_amdgcn_mfma_f32_16x16x32_bf16(a, b, acc[nt], 0, 0, 0);
        }
    }
#pragma unroll
    for (int r = 0; r < 4; ++r) {
        const int gr = blockIdx.x * 16 + quad * 4 + r;
        const bool okr = gr < nN;
        const float d = okr ? dinv[gr] : 0.f;
#pragma unroll
        for (int nt = 0; nt < 2; ++nt) {
            float val = d * acc[nt][r];
            float vo = __shfl_xor(val, 1, 64);
            if (okr && !(l16 & 1)) {
                __builtin_nontemporal_store(
                    f2bf(val) | (f2bf(vo) << 16),
                    Pout32 + (size_t)gr * 64 + (wave * 2 + nt) * 8 + (l16 >> 1));
            }
        }
    }
}

// Final layer: agg fused into mean-pool partial sums.
__global__ __launch_bounds__(256) void agg_pool(const uint4* __restrict__ Pb,
                                                const int* __restrict__ rowptr,
                                                const int* __restrict__ ssrc,
                                                const float* __restrict__ dinv,
                                                const float* __restrict__ bias,
                                                const int* __restrict__ batch,
                                                float* __restrict__ psum, int nN) {
    __shared__ float hsf[16][HID];
    __shared__ int sg[16];
    const int lane16 = threadIdx.x & 15;
    const int grp = threadIdx.x >> 4;
    const int v = blockIdx.x * 16 + grp;
    const bool ok = v < nN;
    float a0[8], a1[8], a2[8], a3[8];
#pragma unroll
    for (int i = 0; i < 8; ++i) { a0[i] = 0.f; a1[i] = 0.f; a2[i] = 0.f; a3[i] = 0.f; }
    float hv[8];
#pragma unroll
    for (int i = 0; i < 8; ++i) hv[i] = 0.f;
    if (ok) {
        acc_bf8(Pb[(size_t)v * 16 + lane16], a0);  // self loop
        int e = rowptr[v];
        const int e1 = rowptr[v + 1];
        for (; e + 4 <= e1; e += 4) {
            const int u0 = __builtin_nontemporal_load(ssrc + e + 0);
            const int u1 = __builtin_nontemporal_load(ssrc + e + 1);
            const int u2 = __builtin_nontemporal_load(ssrc + e + 2);
            const int u3 = __builtin_nontemporal_load(ssrc + e + 3);
            uint4 q0 = Pb[(size_t)u0 * 16 + lane16];
            uint4 q1 = Pb[(size_t)u1 * 16 + lane16];
            uint4 q2 = Pb[(size_t)u2 * 16 + lane16];
            uint4 q3 = Pb[(size_t)u3 * 16 + lane16];
            acc_bf8(q0, a0); acc_bf8(q1, a1); acc_bf8(q2, a2); acc_bf8(q3, a3);
        }
        for (; e < e1; ++e) {
            const int u = __builtin_nontemporal_load(ssrc + e);
            uint4 q = Pb[(size_t)u * 16 + lane16];
            acc_bf8(q, a1);
        }
        const float dv = dinv[v];
        const float4 bb0 = ((const float4*)bias)[lane16 * 2];
        const float4 bb1 = ((const float4*)bias)[lane16 * 2 + 1];
        hv[0] = fmaxf(fmaf(dv, (a0[0] + a1[0]) + (a2[0] + a3[0]), bb0.x), 0.f);
        hv[1] = fmaxf(fmaf(dv, (a0[1] + a1[1]) + (a2[1] + a3[1]), bb0.y), 0.f);
        hv[2] = fmaxf(fmaf(dv, (a0[2] + a1[2]) + (a2[2] + a3[2]), bb0.z), 0.f);
        hv[3] = fmaxf(fmaf(dv, (a0[3] + a1[3]) + (a2[3] + a3[3]), bb0.w), 0.f);
        hv[4] = fmaxf(fmaf(dv, (a0[4] + a1[4]) + (a2[4] + a3[4]), bb1.x), 0.f);
        hv[5] = fmaxf(fmaf(dv, (a0[5] + a1[5]) + (a2[5] + a3[5]), bb1.y), 0.f);
        hv[6] = fmaxf(fmaf(dv, (a0[6] + a1[6]) + (a2[6] + a3[6]), bb1.z), 0.f);
        hv[7] = fmaxf(fmaf(dv, (a0[7] + a1[7]) + (a2[7] + a3[7]), bb1.w), 0.f);
    }
#pragma unroll
    for (int j = 0; j < 8; ++j) hsf[grp][lane16 * 8 + j] = hv[j];
    if (lane16 == 0) sg[grp] = ok ? batch[v] : -1;
    __syncthreads();
    // per-graph column sums: threads 0..127 each own one column
    if (threadIdx.x < HID) {
        const int c = threadIdx.x;
        float acc = 0.f;
        int g = sg[0];
#pragma unroll
        for (int i = 0; i < 16; ++i) {
            const int gi = sg[i];
            if (gi != g) {
                if (g >= 0) atomicAdd(&psum[(size_t)g * HID + c], acc);
                g = gi;
                acc = 0.f;
            }
            acc += hsf[i][c];
        }
        if (g >= 0) atomicAdd(&psum[(size_t)g * HID + c], acc);
    }
}

// ---------------------------------------------------------------------------
// pooled mean from psum + single-step LSTM + FC(2); one block (128 thr) per graph
__global__ __launch_bounds__(128) void pool_lstm(const float* __restrict__ psum,
                                                 const int* __restrict__ batch,
                                                 const float* __restrict__ W_ih,
                                                 const float* __restrict__ b_ih,
                                                 const float* __restrict__ b_hh,
                                                 const float* __restrict__ W_fc,
                                                 const float* __restrict__ b_fc,
                                                 float* __restrict__ out, int nN) {
    __shared__ float pv[HID];
    __shared__ float r0[2], r1[2];
    __shared__ int scnt;
    const int g = blockIdx.x, j = threadIdx.x;
    if (j == 0) {
        int lo = 0, hi = nN;
        while (lo < hi) { int m = (lo + hi) >> 1; if (batch[m] < g) lo = m + 1; else hi = m; }
        const int start = lo;
        hi = nN;
        while (lo < hi) { int m = (lo + hi) >> 1; if (batch[m] < g + 1) lo = m + 1; else hi = m; }
        scnt = max(lo - start, 1);
    }
    __syncthreads();
    pv[j] = psum[(size_t)g * HID + j] / (float)scnt;
    __syncthreads();
    float di = b_ih[j] + b_hh[j];
    float dg = b_ih[256 + j] + b_hh[256 + j];
    float dO = b_ih[384 + j] + b_hh[384 + j];
    const float4* pv4 = (const float4*)pv;
#pragma unroll 4
    for (int k4 = 0; k4 < 32; ++k4) {
        float4 p = pv4[k4];
        float4 wi = *(const float4*)(W_ih + (size_t)j * HID + k4 * 4);
        float4 wg = *(const float4*)(W_ih + (size_t)(256 + j) * HID + k4 * 4);
        float4 wo = *(const float4*)(W_ih + (size_t)(384 + j) * HID + k4 * 4);
        di += p.x * wi.x + p.y * wi.y + p.z * wi.z + p.w * wi.w;
        dg += p.x * wg.x + p.y * wg.y + p.z * wg.z + p.w * wg.w;
        dO += p.x * wo.x + p.y * wo.y + p.z * wo.z + p.w * wo.w;
    }
    const float si = 1.0f / (1.0f + expf(-di));
    const float so = 1.0f / (1.0f + expf(-dO));
    const float c = si * tanhf(dg);
    const float hn = so * tanhf(c);
    float p0 = hn * W_fc[j];
    float p1 = hn * W_fc[HID + j];
#pragma unroll
    for (int off = 32; off > 0; off >>= 1) {
        p0 += __shfl_down(p0, off, 64);
        p1 += __shfl_down(p1, off, 64);
    }
    const int w = j >> 6, l = j & 63;
    if (l == 0) { r0[w] = p0; r1[w] = p1; }
    __syncthreads();
    if (j == 0) {
        out[g * 2 + 0] = r0[0] + r0[1] + b_fc[0];
        out[g * 2 + 1] = r1[0] + r1[1] + b_fc[1];
    }
}

// ---------------------------------------------------------------------------
extern "C" void kernel_launch(void* const* d_in, const int* in_sizes, int n_in,
                              void* d_out, int out_size, void* d_ws, size_t ws_size,
                              hipStream_t stream) {
    const float* x      = (const float*)d_in[0];
    const int*   eidx   = (const int*)d_in[1];
    const int*   batch  = (const int*)d_in[2];
    const float* W0     = (const float*)d_in[4];
    const float* b0     = (const float*)d_in[5];
    const float* W1     = (const float*)d_in[6];
    const float* b1     = (const float*)d_in[7];
    const float* W2     = (const float*)d_in[8];
    const float* b2     = (const float*)d_in[9];
    const float* W_ih   = (const float*)d_in[10];
    const float* b_ih   = (const float*)d_in[12];
    const float* b_hh   = (const float*)d_in[13];
    const float* W_fc   = (const float*)d_in[14];
    const float* b_fc   = (const float*)d_in[15];
    float* out = (float*)d_out;

    const int nN = in_sizes[0] / HID;     // 100000
    const int nE = in_sizes[1] / 2;       // 1600000
    const int nG = out_size / 2;          // 256
    const int* src = eidx;
    const int* dst = eidx + nE;
    const int rowsPad = (nN + GEMM_ROWS - 1) & ~(GEMM_ROWS - 1);

    // workspace layout (bcnt and psum adjacent -> single memset)
    size_t off = 0;
    auto alloc = [&](size_t bytes) -> void* {
        void* p = (char*)d_ws + off;
        off += (bytes + 255) & ~(size_t)255;
        return p;
    };
    int*   bcnt   = (int*)alloc(NBUCK_MAX * sizeof(int));             // 2048 B
    float* psum   = (float*)alloc((size_t)nG * HID * sizeof(float));  // 128 KB
    uint4* Pb     = (uint4*)alloc((size_t)nN * 16 * sizeof(uint4));   // bf16 P (ping)
    uint4* Pb2    = (uint4*)alloc((size_t)nN * 16 * sizeof(uint4));   // bf16 P (pong)
    float* dinv   = (float*)alloc((size_t)nN * sizeof(float));
    int*   rowptr = (int*)alloc((size_t)(nN + 1) * sizeof(int));
    int*   ssrc   = (int*)alloc((size_t)nE * sizeof(int));
    unsigned int* ebuf = (unsigned int*)alloc((size_t)nE * sizeof(unsigned int));
    int*   boff   = (int*)alloc(NBUCK_MAX * sizeof(int));
    int*   bcur   = (int*)alloc(NBUCK_MAX * sizeof(int));
    unsigned short* Wtb = (unsigned short*)alloc(3 * HID * HID * sizeof(unsigned short));
    (void)ws_size;

    const int nB = (nN + 255) >> 8;
    const int tileBlocks = (nE + EDGE_TILE - 1) / EDGE_TILE;

    // single combined memset (bcnt + psum are adjacent, both 256B-aligned)
    hipMemsetAsync(bcnt, 0, NBUCK_MAX * sizeof(int) + (size_t)nG * HID * sizeof(float),
                   stream);

    // multisplit: bucket-sort edges (packed 4B) by dst bucket; wt fused in pass 1
    bucket_count_wt<<<tileBlocks, 256, 0, stream>>>(dst, bcnt, W0, W1, W2, Wtb, nE, nB);
    bucket_scan<<<1, 512, 0, stream>>>(bcnt, boff, bcur, nB);
    bucket_scatter<<<tileBlocks, 256, 0, stream>>>(src, dst, bcur, ebuf, nE, nB);

    // merged CSR build: degrees + dinv + rowptr + scatter in one dispatch
    csr_build<<<nB, 256, 0, stream>>>(ebuf, boff, dinv, rowptr, ssrc, nE, nB, nN);

    const int gemmBlocks = rowsPad / GEMM_ROWS;
    const int aggBlocks = (nN + 15) / 16;
    const uint4* Wt1 = (const uint4*)(Wtb + HID * HID);
    const uint4* Wt2 = (const uint4*)(Wtb + 2 * HID * HID);

    // layer 0 GEMM (fp32 in), then fused agg0+gemm1, fused agg1+gemm2,
    // then final agg fused into pool partial sums
    gemm_mfma_f32in<<<gemmBlocks, 256, 0, stream>>>(x, (const uint4*)Wtb, dinv,
                                                    (unsigned int*)Pb, nN);
    fused_agg_gemm<<<aggBlocks, 256, 0, stream>>>(Pb, rowptr, ssrc, dinv, b0, Wt1,
                                                  (unsigned int*)Pb2, nN);
    fused_agg_gemm<<<aggBlocks, 256, 0, stream>>>(Pb2, rowptr, ssrc, dinv, b1, Wt2,
                                                  (unsigned int*)Pb, nN);
    agg_pool<<<aggBlocks, 256, 0, stream>>>(Pb, rowptr, ssrc, dinv, b2, batch, psum, nN);

    // pooled mean + LSTM + FC (one 128-thread block per graph)
    pool_lstm<<<nG, 128, 0, stream>>>(psum, batch, W_ih, b_ih, b_hh, W_fc, b_fc,
                                      out, nN);
}

// Round 7
// 435.104 us; speedup vs baseline: 1.0741x; 1.0741x over previous
//
#include <hip/hip_runtime.h>
#include <math.h>
#include <stdint.h>

#define HID 128
#define NBUCK_MAX 512     // node buckets of 256 nodes each (nN<=131072)
#define EDGE_TILE 8192    // edges per block in bucket passes
#define GEMM_ROWS 128     // M-tile per block (layer-0 gemm)
#define XS_STRIDE 136     // bf16 elems per LDS row (128 + 8 pad)

typedef short bf16x8 __attribute__((ext_vector_type(8)));
typedef float f32x4 __attribute__((ext_vector_type(4)));

// ---------------------------------------------------------------------------
// round-to-nearest-even fp32 -> bf16 bits
__device__ __forceinline__ unsigned int f2bf(float f) {
    union { float f; uint32_t i; } u; u.f = f;
    uint32_t r = u.i + 0x7fffu + ((u.i >> 16) & 1u);
    return r >> 16;
}
__device__ __forceinline__ float bf2f_lo(uint32_t x) {
    union { uint32_t i; float f; } t; t.i = x << 16; return t.f;
}
__device__ __forceinline__ float bf2f_hi(uint32_t x) {
    union { uint32_t i; float f; } t; t.i = x & 0xffff0000u; return t.f;
}

// ---------------------------------------------------------------------------
// Multisplit pass 1: per-bucket counts (bucket = dst >> 8) + fused weight
// transpose/convert: Wt[n][k] = bf16(W[k][n]), 3 x 128 x 128.
__global__ __launch_bounds__(256) void bucket_count_wt(const int* __restrict__ dst,
                                                       int* __restrict__ bcnt,
                                                       const float* __restrict__ W0,
                                                       const float* __restrict__ W1,
                                                       const float* __restrict__ W2,
                                                       unsigned short* __restrict__ Wtb,
                                                       int nE, int nB) {
    __shared__ int h[NBUCK_MAX];
    const int gid = blockIdx.x * 256 + threadIdx.x;
    if (gid < 3 * HID * HID) {          // fused weight transpose (49152 elems)
        int w = gid >> 14, r = gid & 16383;
        int n = r >> 7, k = r & 127;
        const float* W = (w == 0) ? W0 : (w == 1) ? W1 : W2;
        Wtb[gid] = (unsigned short)f2bf(W[k * HID + n]);
    }
    for (int i = threadIdx.x; i < nB; i += 256) h[i] = 0;
    __syncthreads();
    const int base = blockIdx.x * EDGE_TILE;
    const int end = min(base + EDGE_TILE, nE);
    for (int e = base + threadIdx.x; e < end; e += 256)
        atomicAdd(&h[dst[e] >> 8], 1);
    __syncthreads();
    for (int i = threadIdx.x; i < nB; i += 256)
        if (h[i]) atomicAdd(&bcnt[i], h[i]);
}

__global__ __launch_bounds__(512) void bucket_scan(const int* __restrict__ bcnt,
                                                   int* __restrict__ boff,
                                                   int* __restrict__ bcur, int nB) {
    __shared__ int sd[512];
    const int t = threadIdx.x;
    sd[t] = (t < nB) ? bcnt[t] : 0;
    __syncthreads();
#pragma unroll
    for (int off = 1; off < 512; off <<= 1) {
        int v = sd[t];
        int add = (t >= off) ? sd[t - off] : 0;
        __syncthreads();
        sd[t] = v + add;
        __syncthreads();
    }
    if (t < nB) {
        int ex = (t > 0) ? sd[t - 1] : 0;
        boff[t] = ex;
        bcur[t] = ex;
    }
}

__global__ __launch_bounds__(256) void bucket_scatter(const int* __restrict__ src,
                                                      const int* __restrict__ dst,
                                                      int* __restrict__ bcur,
                                                      unsigned int* __restrict__ ebuf,
                                                      int nE, int nB) {
    __shared__ int h[NBUCK_MAX];
    __shared__ int basearr[NBUCK_MAX];
    const int base = blockIdx.x * EDGE_TILE;
    const int end = min(base + EDGE_TILE, nE);
    for (int i = threadIdx.x; i < nB; i += 256) h[i] = 0;
    __syncthreads();
    for (int e = base + threadIdx.x; e < end; e += 256)
        atomicAdd(&h[dst[e] >> 8], 1);
    __syncthreads();
    for (int i = threadIdx.x; i < nB; i += 256) {
        int c = h[i];
        basearr[i] = c ? atomicAdd(&bcur[i], c) : 0;
        h[i] = 0;   // reuse as local cursor
    }
    __syncthreads();
    for (int e = base + threadIdx.x; e < end; e += 256) {
        int d = dst[e];
        int b = d >> 8;
        int pos = basearr[b] + atomicAdd(&h[b], 1);
        ebuf[pos] = ((unsigned)src[e] << 8) | ((unsigned)d & 255u);
    }
}

// ---------------------------------------------------------------------------
// Merged CSR build: one block per 256-node bucket. boff[b] (bucket-boundary
// edge prefix) IS the global CSR prefix, so no inter-block scan is needed.
// histogram -> local exclusive scan (+boff[b]) -> rowptr/dinv -> in-LDS scatter.
__global__ __launch_bounds__(256) void csr_build(const unsigned int* __restrict__ ebuf,
                                                 const int* __restrict__ boff,
                                                 float* __restrict__ dinv,
                                                 int* __restrict__ rowptr,
                                                 int* __restrict__ ssrc,
                                                 int nE, int nB, int nN) {
    __shared__ int h[256];
    __shared__ int rp[256];
    const int b = blockIdx.x, t = threadIdx.x;
    const int e0 = boff[b];
    const int e1 = (b + 1 < nB) ? boff[b + 1] : nE;
    h[t] = 0;
    __syncthreads();
    for (int e = e0 + t; e < e1; e += 256)
        atomicAdd(&h[ebuf[e] & 255u], 1);
    __syncthreads();
    const int c = h[t];
    rp[t] = c;
    __syncthreads();
#pragma unroll
    for (int off = 1; off < 256; off <<= 1) {
        int v = rp[t];
        int add = (t >= off) ? rp[t - off] : 0;
        __syncthreads();
        rp[t] = v + add;
        __syncthreads();
    }
    const int pre = e0 + rp[t] - c;     // exclusive global prefix for node
    const int v = b * 256 + t;
    if (v < nN) {
        rowptr[v] = pre;
        dinv[v] = rsqrtf((float)c + 1.0f);
    }
    if (b == 0 && t == 0) rowptr[nN] = nE;
    __syncthreads();
    rp[t] = pre;                        // scatter base
    h[t] = 0;                           // cursor
    __syncthreads();
    for (int e = e0 + t; e < e1; e += 256) {
        unsigned int ed = ebuf[e];
        int li = (int)(ed & 255u);
        int pos = rp[li] + atomicAdd(&h[li], 1);
        ssrc[pos] = (int)(ed >> 8);
    }
}

// ---------------------------------------------------------------------------
// Layer-0 MFMA GEMM with fused fp32->bf16 input conversion.
// Pb = bf16(dinv ⊙ (bf16(X) @ W)), fp32 accumulate.
__global__ __launch_bounds__(256) void gemm_mfma_f32in(const float* __restrict__ X,
                                                       const uint4* __restrict__ Wtb,
                                                       const float* __restrict__ dinv,
                                                       unsigned int* __restrict__ Pb32,
                                                       int nN) {
    __shared__ short Xs[GEMM_ROWS * XS_STRIDE];
    __shared__ short Ws[HID * XS_STRIDE];
    const int tid = threadIdx.x;
    const int rowBase = blockIdx.x * GEMM_ROWS;
#pragma unroll
    for (int it = 0; it < 16; ++it) {  // 4096 float4 X-tile, convert to bf16
        int f = it * 256 + tid;
        int row = f >> 5, c = f & 31;
        int grow = rowBase + row;
        float4 v = make_float4(0.f, 0.f, 0.f, 0.f);
        if (grow < nN) v = *(const float4*)(X + (size_t)grow * HID + c * 4);
        uint2 o;
        o.x = f2bf(v.x) | (f2bf(v.y) << 16);
        o.y = f2bf(v.z) | (f2bf(v.w) << 16);
        *(uint2*)(&Xs[row * XS_STRIDE + c * 4]) = o;
    }
#pragma unroll
    for (int it = 0; it < 8; ++it) {   // 2048 uint4 W-tile
        int f = it * 256 + tid;
        int n = f >> 4, c = f & 15;
        *(uint4*)(&Ws[n * XS_STRIDE + c * 8]) = Wtb[f];
    }
    __syncthreads();
    const int wave = tid >> 6, lane = tid & 63;
    const int quad = lane >> 4, l16 = lane & 15;
    f32x4 acc[2][8] = {};
    const int kq = quad * 8;
#pragma unroll
    for (int ks = 0; ks < 4; ++ks) {
        const int k0 = ks * 32 + kq;
        bf16x8 a0 = *(const bf16x8*)(&Xs[(wave * 32 + l16) * XS_STRIDE + k0]);
        bf16x8 a1 = *(const bf16x8*)(&Xs[(wave * 32 + 16 + l16) * XS_STRIDE + k0]);
#pragma unroll
        for (int nt = 0; nt < 8; ++nt) {
            bf16x8 b = *(const bf16x8*)(&Ws[(nt * 16 + l16) * XS_STRIDE + k0]);
            acc[0][nt] = __builtin_amdgcn_mfma_f32_16x16x32_bf16(a0, b, acc[0][nt], 0, 0, 0);
            acc[1][nt] = __builtin_amdgcn_mfma_f32_16x16x32_bf16(a1, b, acc[1][nt], 0, 0, 0);
        }
    }
#pragma unroll
    for (int mt = 0; mt < 2; ++mt) {
        const int gr0 = rowBase + wave * 32 + mt * 16 + quad * 4;
#pragma unroll
        for (int r = 0; r < 4; ++r) {
            const int gr = gr0 + r;
            const bool ok = gr < nN;
            const float d = ok ? dinv[gr] : 0.f;
#pragma unroll
            for (int nt = 0; nt < 8; ++nt) {
                float v = d * acc[mt][nt][r];
                float vo = __shfl_xor(v, 1, 64);
                if (ok && !(l16 & 1)) {
                    Pb32[(size_t)gr * 64 + nt * 8 + (l16 >> 1)] = f2bf(v) | (f2bf(vo) << 16);
                }
            }
        }
    }
}

// ---------------------------------------------------------------------------
// unpack 8 bf16 (uint4) and accumulate into 8 fp32
__device__ __forceinline__ void acc_bf8(const uint4 q, float* a) {
    union { uint32_t i; float f; } t;
    t.i = q.x << 16;          a[0] += t.f;
    t.i = q.x & 0xffff0000u;  a[1] += t.f;
    t.i = q.y << 16;          a[2] += t.f;
    t.i = q.y & 0xffff0000u;  a[3] += t.f;
    t.i = q.z << 16;          a[4] += t.f;
    t.i = q.z & 0xffff0000u;  a[5] += t.f;
    t.i = q.w << 16;          a[6] += t.f;
    t.i = q.w & 0xffff0000u;  a[7] += t.f;
}

// Fused agg + next-layer GEMM:
// h[v] = relu(dinv[v]*(P[v] + sum_in P[src]) + b)   (gather phase, registers)
// Pout[v] = bf16(dinv[v] * (h @ Wnext)[v])          (LDS h-tile + MFMA)
// Block = 256 threads = 16 nodes (16 lanes each); 4 waves each do m16 x n32.
__global__ __launch_bounds__(256) void fused_agg_gemm(const uint4* __restrict__ Pb,
                                                      const int* __restrict__ rowptr,
                                                      const int* __restrict__ ssrc,
                                                      const float* __restrict__ dinv,
                                                      const float* __restrict__ bias,
                                                      const uint4* __restrict__ Wtb,
                                                      unsigned int* __restrict__ Pout32,
                                                      int nN) {
    __shared__ short Ws[HID * XS_STRIDE];  // 34816 B
    __shared__ short Hs[16 * XS_STRIDE];   //  4352 B
    const int tid = threadIdx.x;
#pragma unroll
    for (int it = 0; it < 8; ++it) {       // stage W (2048 uint4)
        int f = it * 256 + tid;
        int n = f >> 4, c = f & 15;
        *(uint4*)(&Ws[n * XS_STRIDE + c * 8]) = Wtb[f];
    }
    const int lane16 = tid & 15;
    const int grp = tid >> 4;
    const int v = blockIdx.x * 16 + grp;
    const bool ok = v < nN;
    float a0[8], a1[8], a2[8], a3[8];
#pragma unroll
    for (int i = 0; i < 8; ++i) { a0[i] = 0.f; a1[i] = 0.f; a2[i] = 0.f; a3[i] = 0.f; }
    uint4 q = make_uint4(0u, 0u, 0u, 0u);
    if (ok) {
        acc_bf8(Pb[(size_t)v * 16 + lane16], a0);  // self loop
        int e = rowptr[v];
        const int e1 = rowptr[v + 1];
        for (; e + 4 <= e1; e += 4) {
            const int u0 = ssrc[e + 0], u1 = ssrc[e + 1], u2 = ssrc[e + 2], u3 = ssrc[e + 3];
            uint4 q0 = Pb[(size_t)u0 * 16 + lane16];
            uint4 q1 = Pb[(size_t)u1 * 16 + lane16];
            uint4 q2 = Pb[(size_t)u2 * 16 + lane16];
            uint4 q3 = Pb[(size_t)u3 * 16 + lane16];
            acc_bf8(q0, a0); acc_bf8(q1, a1); acc_bf8(q2, a2); acc_bf8(q3, a3);
        }
        for (; e < e1; ++e) {
            uint4 qe = Pb[(size_t)ssrc[e] * 16 + lane16];
            acc_bf8(qe, a1);
        }
        const float dv = dinv[v];
        const float4 bb0 = ((const float4*)bias)[lane16 * 2];
        const float4 bb1 = ((const float4*)bias)[lane16 * 2 + 1];
        float4 o0, o1;
        o0.x = fmaxf(fmaf(dv, (a0[0] + a1[0]) + (a2[0] + a3[0]), bb0.x), 0.f);
        o0.y = fmaxf(fmaf(dv, (a0[1] + a1[1]) + (a2[1] + a3[1]), bb0.y), 0.f);
        o0.z = fmaxf(fmaf(dv, (a0[2] + a1[2]) + (a2[2] + a3[2]), bb0.z), 0.f);
        o0.w = fmaxf(fmaf(dv, (a0[3] + a1[3]) + (a2[3] + a3[3]), bb0.w), 0.f);
        o1.x = fmaxf(fmaf(dv, (a0[4] + a1[4]) + (a2[4] + a3[4]), bb1.x), 0.f);
        o1.y = fmaxf(fmaf(dv, (a0[5] + a1[5]) + (a2[5] + a3[5]), bb1.y), 0.f);
        o1.z = fmaxf(fmaf(dv, (a0[6] + a1[6]) + (a2[6] + a3[6]), bb1.z), 0.f);
        o1.w = fmaxf(fmaf(dv, (a0[7] + a1[7]) + (a2[7] + a3[7]), bb1.w), 0.f);
        q.x = f2bf(o0.x) | (f2bf(o0.y) << 16);
        q.y = f2bf(o0.z) | (f2bf(o0.w) << 16);
        q.z = f2bf(o1.x) | (f2bf(o1.y) << 16);
        q.w = f2bf(o1.z) | (f2bf(o1.w) << 16);
    }
    *(uint4*)(&Hs[grp * XS_STRIDE + lane16 * 8]) = q;  // bf16 h row tile
    __syncthreads();
    // MFMA: each wave computes the 16-row tile x its 32 cols
    const int wave = tid >> 6, lane = tid & 63;
    const int quad = lane >> 4, l16 = lane & 15;
    f32x4 acc[2] = {};
#pragma unroll
    for (int ks = 0; ks < 4; ++ks) {
        const int k0 = ks * 32 + quad * 8;
        bf16x8 a = *(const bf16x8*)(&Hs[l16 * XS_STRIDE + k0]);
#pragma unroll
        for (int nt = 0; nt < 2; ++nt) {
            bf16x8 b = *(const bf16x8*)(&Ws[((wave * 2 + nt) * 16 + l16) * XS_STRIDE + k0]);
            acc[nt] = __builtin_amdgcn_mfma_f32_16x16x32_bf16(a, b, acc[nt], 0, 0, 0);
        }
    }
#pragma unroll
    for (int r = 0; r < 4; ++r) {
        const int gr = blockIdx.x * 16 + quad * 4 + r;
        const bool okr = gr < nN;
        const float d = okr ? dinv[gr] : 0.f;
#pragma unroll
        for (int nt = 0; nt < 2; ++nt) {
            float val = d * acc[nt][r];
            float vo = __shfl_xor(val, 1, 64);
            if (okr && !(l16 & 1)) {
                Pout32[(size_t)gr * 64 + (wave * 2 + nt) * 8 + (l16 >> 1)] =
                    f2bf(val) | (f2bf(vo) << 16);
            }
        }
    }
}

// Final layer: agg fused into mean-pool partial sums.
__global__ __launch_bounds__(256) void agg_pool(const uint4* __restrict__ Pb,
                                                const int* __restrict__ rowptr,
                                                const int* __restrict__ ssrc,
                                                const float* __restrict__ dinv,
                                                const float* __restrict__ bias,
                                                const int* __restrict__ batch,
                                                float* __restrict__ psum, int nN) {
    __shared__ float hsf[16][HID];
    __shared__ int sg[16];
    const int lane16 = threadIdx.x & 15;
    const int grp = threadIdx.x >> 4;
    const int v = blockIdx.x * 16 + grp;
    const bool ok = v < nN;
    float a0[8], a1[8], a2[8], a3[8];
#pragma unroll
    for (int i = 0; i < 8; ++i) { a0[i] = 0.f; a1[i] = 0.f; a2[i] = 0.f; a3[i] = 0.f; }
    float hv[8];
#pragma unroll
    for (int i = 0; i < 8; ++i) hv[i] = 0.f;
    if (ok) {
        acc_bf8(Pb[(size_t)v * 16 + lane16], a0);  // self loop
        int e = rowptr[v];
        const int e1 = rowptr[v + 1];
        for (; e + 4 <= e1; e += 4) {
            const int u0 = ssrc[e + 0], u1 = ssrc[e + 1], u2 = ssrc[e + 2], u3 = ssrc[e + 3];
            uint4 q0 = Pb[(size_t)u0 * 16 + lane16];
            uint4 q1 = Pb[(size_t)u1 * 16 + lane16];
            uint4 q2 = Pb[(size_t)u2 * 16 + lane16];
            uint4 q3 = Pb[(size_t)u3 * 16 + lane16];
            acc_bf8(q0, a0); acc_bf8(q1, a1); acc_bf8(q2, a2); acc_bf8(q3, a3);
        }
        for (; e < e1; ++e) {
            uint4 q = Pb[(size_t)ssrc[e] * 16 + lane16];
            acc_bf8(q, a1);
        }
        const float dv = dinv[v];
        const float4 bb0 = ((const float4*)bias)[lane16 * 2];
        const float4 bb1 = ((const float4*)bias)[lane16 * 2 + 1];
        hv[0] = fmaxf(fmaf(dv, (a0[0] + a1[0]) + (a2[0] + a3[0]), bb0.x), 0.f);
        hv[1] = fmaxf(fmaf(dv, (a0[1] + a1[1]) + (a2[1] + a3[1]), bb0.y), 0.f);
        hv[2] = fmaxf(fmaf(dv, (a0[2] + a1[2]) + (a2[2] + a3[2]), bb0.z), 0.f);
        hv[3] = fmaxf(fmaf(dv, (a0[3] + a1[3]) + (a2[3] + a3[3]), bb0.w), 0.f);
        hv[4] = fmaxf(fmaf(dv, (a0[4] + a1[4]) + (a2[4] + a3[4]), bb1.x), 0.f);
        hv[5] = fmaxf(fmaf(dv, (a0[5] + a1[5]) + (a2[5] + a3[5]), bb1.y), 0.f);
        hv[6] = fmaxf(fmaf(dv, (a0[6] + a1[6]) + (a2[6] + a3[6]), bb1.z), 0.f);
        hv[7] = fmaxf(fmaf(dv, (a0[7] + a1[7]) + (a2[7] + a3[7]), bb1.w), 0.f);
    }
#pragma unroll
    for (int j = 0; j < 8; ++j) hsf[grp][lane16 * 8 + j] = hv[j];
    if (lane16 == 0) sg[grp] = ok ? batch[v] : -1;
    __syncthreads();
    // per-graph column sums: threads 0..127 each own one column
    if (threadIdx.x < HID) {
        const int c = threadIdx.x;
        float acc = 0.f;
        int g = sg[0];
#pragma unroll
        for (int i = 0; i < 16; ++i) {
            const int gi = sg[i];
            if (gi != g) {
                if (g >= 0) atomicAdd(&psum[(size_t)g * HID + c], acc);
                g = gi;
                acc = 0.f;
            }
            acc += hsf[i][c];
        }
        if (g >= 0) atomicAdd(&psum[(size_t)g * HID + c], acc);
    }
}

// ---------------------------------------------------------------------------
// pooled mean from psum + single-step LSTM + FC(2); one block (128 thr) per graph
__global__ __launch_bounds__(128) void pool_lstm(const float* __restrict__ psum,
                                                 const int* __restrict__ batch,
                                                 const float* __restrict__ W_ih,
                                                 const float* __restrict__ b_ih,
                                                 const float* __restrict__ b_hh,
                                                 const float* __restrict__ W_fc,
                                                 const float* __restrict__ b_fc,
                                                 float* __restrict__ out, int nN) {
    __shared__ float pv[HID];
    __shared__ float r0[2], r1[2];
    __shared__ int scnt;
    const int g = blockIdx.x, j = threadIdx.x;
    if (j == 0) {
        int lo = 0, hi = nN;
        while (lo < hi) { int m = (lo + hi) >> 1; if (batch[m] < g) lo = m + 1; else hi = m; }
        const int start = lo;
        hi = nN;
        while (lo < hi) { int m = (lo + hi) >> 1; if (batch[m] < g + 1) lo = m + 1; else hi = m; }
        scnt = max(lo - start, 1);
    }
    __syncthreads();
    pv[j] = psum[(size_t)g * HID + j] / (float)scnt;
    __syncthreads();
    float di = b_ih[j] + b_hh[j];
    float dg = b_ih[256 + j] + b_hh[256 + j];
    float dO = b_ih[384 + j] + b_hh[384 + j];
    const float4* pv4 = (const float4*)pv;
#pragma unroll 4
    for (int k4 = 0; k4 < 32; ++k4) {
        float4 p = pv4[k4];
        float4 wi = *(const float4*)(W_ih + (size_t)j * HID + k4 * 4);
        float4 wg = *(const float4*)(W_ih + (size_t)(256 + j) * HID + k4 * 4);
        float4 wo = *(const float4*)(W_ih + (size_t)(384 + j) * HID + k4 * 4);
        di += p.x * wi.x + p.y * wi.y + p.z * wi.z + p.w * wi.w;
        dg += p.x * wg.x + p.y * wg.y + p.z * wg.z + p.w * wg.w;
        dO += p.x * wo.x + p.y * wo.y + p.z * wo.z + p.w * wo.w;
    }
    const float si = 1.0f / (1.0f + expf(-di));
    const float so = 1.0f / (1.0f + expf(-dO));
    const float c = si * tanhf(dg);
    const float hn = so * tanhf(c);
    float p0 = hn * W_fc[j];
    float p1 = hn * W_fc[HID + j];
#pragma unroll
    for (int off = 32; off > 0; off >>= 1) {
        p0 += __shfl_down(p0, off, 64);
        p1 += __shfl_down(p1, off, 64);
    }
    const int w = j >> 6, l = j & 63;
    if (l == 0) { r0[w] = p0; r1[w] = p1; }
    __syncthreads();
    if (j == 0) {
        out[g * 2 + 0] = r0[0] + r0[1] + b_fc[0];
        out[g * 2 + 1] = r1[0] + r1[1] + b_fc[1];
    }
}

// ---------------------------------------------------------------------------
extern "C" void kernel_launch(void* const* d_in, const int* in_sizes, int n_in,
                              void* d_out, int out_size, void* d_ws, size_t ws_size,
                              hipStream_t stream) {
    const float* x      = (const float*)d_in[0];
    const int*   eidx   = (const int*)d_in[1];
    const int*   batch  = (const int*)d_in[2];
    const float* W0     = (const float*)d_in[4];
    const float* b0     = (const float*)d_in[5];
    const float* W1     = (const float*)d_in[6];
    const float* b1     = (const float*)d_in[7];
    const float* W2     = (const float*)d_in[8];
    const float* b2     = (const float*)d_in[9];
    const float* W_ih   = (const float*)d_in[10];
    const float* b_ih   = (const float*)d_in[12];
    const float* b_hh   = (const float*)d_in[13];
    const float* W_fc   = (const float*)d_in[14];
    const float* b_fc   = (const float*)d_in[15];
    float* out = (float*)d_out;

    const int nN = in_sizes[0] / HID;     // 100000
    const int nE = in_sizes[1] / 2;       // 1600000
    const int nG = out_size / 2;          // 256
    const int* src = eidx;
    const int* dst = eidx + nE;
    const int rowsPad = (nN + GEMM_ROWS - 1) & ~(GEMM_ROWS - 1);

    // workspace layout (bcnt and psum adjacent -> single memset)
    size_t off = 0;
    auto alloc = [&](size_t bytes) -> void* {
        void* p = (char*)d_ws + off;
        off += (bytes + 255) & ~(size_t)255;
        return p;
    };
    int*   bcnt   = (int*)alloc(NBUCK_MAX * sizeof(int));             // 2048 B
    float* psum   = (float*)alloc((size_t)nG * HID * sizeof(float));  // 128 KB
    uint4* Pb     = (uint4*)alloc((size_t)nN * 16 * sizeof(uint4));   // bf16 P (ping)
    uint4* Pb2    = (uint4*)alloc((size_t)nN * 16 * sizeof(uint4));   // bf16 P (pong)
    float* dinv   = (float*)alloc((size_t)nN * sizeof(float));
    int*   rowptr = (int*)alloc((size_t)(nN + 1) * sizeof(int));
    int*   ssrc   = (int*)alloc((size_t)nE * sizeof(int));
    unsigned int* ebuf = (unsigned int*)alloc((size_t)nE * sizeof(unsigned int));
    int*   boff   = (int*)alloc(NBUCK_MAX * sizeof(int));
    int*   bcur   = (int*)alloc(NBUCK_MAX * sizeof(int));
    unsigned short* Wtb = (unsigned short*)alloc(3 * HID * HID * sizeof(unsigned short));
    (void)ws_size;

    const int nB = (nN + 255) >> 8;
    const int tileBlocks = (nE + EDGE_TILE - 1) / EDGE_TILE;

    // single combined memset (bcnt + psum are adjacent, both 256B-aligned)
    hipMemsetAsync(bcnt, 0, NBUCK_MAX * sizeof(int) + (size_t)nG * HID * sizeof(float),
                   stream);

    // multisplit: bucket-sort edges (packed 4B) by dst bucket; wt fused in pass 1
    bucket_count_wt<<<tileBlocks, 256, 0, stream>>>(dst, bcnt, W0, W1, W2, Wtb, nE, nB);
    bucket_scan<<<1, 512, 0, stream>>>(bcnt, boff, bcur, nB);
    bucket_scatter<<<tileBlocks, 256, 0, stream>>>(src, dst, bcur, ebuf, nE, nB);

    // merged CSR build: degrees + dinv + rowptr + scatter in one dispatch
    csr_build<<<nB, 256, 0, stream>>>(ebuf, boff, dinv, rowptr, ssrc, nE, nB, nN);

    const int gemmBlocks = rowsPad / GEMM_ROWS;
    const int aggBlocks = (nN + 15) / 16;
    const uint4* Wt1 = (const uint4*)(Wtb + HID * HID);
    const uint4* Wt2 = (const uint4*)(Wtb + 2 * HID * HID);

    // layer 0 GEMM (fp32 in), then fused agg0+gemm1, fused agg1+gemm2,
    // then final agg fused into pool partial sums
    gemm_mfma_f32in<<<gemmBlocks, 256, 0, stream>>>(x, (const uint4*)Wtb, dinv,
                                                    (unsigned int*)Pb, nN);
    fused_agg_gemm<<<aggBlocks, 256, 0, stream>>>(Pb, rowptr, ssrc, dinv, b0, Wt1,
                                                  (unsigned int*)Pb2, nN);
    fused_agg_gemm<<<aggBlocks, 256, 0, stream>>>(Pb2, rowptr, ssrc, dinv, b1, Wt2,
                                                  (unsigned int*)Pb, nN);
    agg_pool<<<aggBlocks, 256, 0, stream>>>(Pb, rowptr, ssrc, dinv, b2, batch, psum, nN);

    // pooled mean + LSTM + FC (one 128-thread block per graph)
    pool_lstm<<<nG, 128, 0, stream>>>(psum, batch, W_ih, b_ih, b_hh, W_fc, b_fc,
                                      out, nN);
}